// Round 9
// baseline (39.391 us; speedup 1.0000x reference)
//
#include <hip/hip_runtime.h>

#define N1 4096
#define N2 8192
#define FDIM 256
#define HDIM 128
#define OUTD 128

typedef float fx4 __attribute__((ext_vector_type(4)));

// mish(x) = x * tanh(softplus(x)) = x - 2x/(w^2+1), w = 1+e^x
__device__ __forceinline__ float mishf(float x) {
    float e = __expf(fminf(x, 30.0f));
    float w = 1.0f + e;
    float q = __builtin_fmaf(w, w, 1.0f);      // w^2 + 1
    float r = __builtin_amdgcn_rcpf(q);
    return __builtin_fmaf(x, -2.0f * r, x);    // x - 2x/q
}

// 512 waves, one per output element: v[c] = dot(w[c,:], a-slice).
__global__ void compute_v_kernel(const float* __restrict__ w_m,
                                 const float* __restrict__ w_d,
                                 const float* __restrict__ a,
                                 float* __restrict__ v /* 512 floats: v_m | v_d */) {
    int wave = (blockIdx.x << 2) + (threadIdx.x >> 6);   // 0..511
    int lane = threadIdx.x & 63;
    const float* wr = (wave < 256) ? (w_m + wave * OUTD) : (w_d + (wave - 256) * OUTD);
    const float* av = (wave < 256) ? a : (a + 2 * OUTD);
    float2 wv = ((const float2*)wr)[lane];
    float2 aa = ((const float2*)av)[lane];
    float s = wv.x * aa.x + wv.y * aa.y;
    #pragma unroll
    for (int off = 32; off > 0; off >>= 1) s += __shfl_down(s, off, 64);
    if (lane == 0) v[wave] = s;
}

// y only: one wave per d-row. y[j] = sum_c (ad0*d+ad1*d1+ad2*d2)[j,c]*v_d[c]
//                                   + sum_h d_h[j,h]*a2h[h]
__global__ void compute_y_kernel(const float* __restrict__ d,  const float* __restrict__ d1,
                                 const float* __restrict__ d2, const float* __restrict__ d_h,
                                 const float* __restrict__ a_d,
                                 const float* __restrict__ a,
                                 const float* __restrict__ v,
                                 float* __restrict__ y /* 8192 floats */) {
    int gtid = blockIdx.x * blockDim.x + threadIdx.x;
    int row  = gtid >> 6;                 // 0..8191
    int lane = threadIdx.x & 63;
    float c0 = a_d[0], c1 = a_d[1], c2 = a_d[2];

    fx4 v0 = ((const fx4*)(d  + (size_t)row * FDIM))[lane];
    fx4 v1 = ((const fx4*)(d1 + (size_t)row * FDIM))[lane];
    fx4 v2 = ((const fx4*)(d2 + (size_t)row * FDIM))[lane];
    fx4 vv = ((const fx4*)(v + 256))[lane];

    float val = (c0 * v0.x + c1 * v1.x + c2 * v2.x) * vv.x
              + (c0 * v0.y + c1 * v1.y + c2 * v2.y) * vv.y
              + (c0 * v0.z + c1 * v1.z + c2 * v2.z) * vv.z
              + (c0 * v0.w + c1 * v1.w + c2 * v2.w) * vv.w;

    if (lane < 32) {
        fx4 hv = ((const fx4*)(d_h + (size_t)row * HDIM))[lane];
        fx4 av = ((const fx4*)(a + 2 * OUTD + HDIM))[lane];
        val += hv.x * av.x + hv.y * av.y + hv.z * av.z + hv.w * av.w;
    }

    #pragma unroll
    for (int off = 32; off > 0; off >>= 1) val += __shfl_down(val, off, 64);
    if (lane == 0) y[row] = val;
}

// Fused x + broadcast: one wave per output row (4096 waves, 1024 blocks).
// Wave computes x[row] from the m-side (reads hidden under the global store
// stream of other waves), lane-broadcasts it, then streams its 32 KB row:
// 16 iterations x (2 y-loads from L1 + 16 mish + 2 coalesced 1 KB stores).
__global__ void mish_xbcast_kernel(const float* __restrict__ m,  const float* __restrict__ m1,
                                   const float* __restrict__ m2, const float* __restrict__ m_h,
                                   const float* __restrict__ a_m,
                                   const float* __restrict__ a,
                                   const float* __restrict__ v,
                                   const float* __restrict__ y,
                                   fx4* __restrict__ out) {
    const int row  = (blockIdx.x << 2) + (threadIdx.x >> 6);   // 0..4095
    const int lane = threadIdx.x & 63;
    const float c0 = a_m[0], c1 = a_m[1], c2 = a_m[2];

    // ---- x[row] ----
    fx4 v0 = ((const fx4*)(m  + (size_t)row * FDIM))[lane];
    fx4 v1 = ((const fx4*)(m1 + (size_t)row * FDIM))[lane];
    fx4 v2 = ((const fx4*)(m2 + (size_t)row * FDIM))[lane];
    fx4 vv = ((const fx4*)v)[lane];

    float val = (c0 * v0.x + c1 * v1.x + c2 * v2.x) * vv.x
              + (c0 * v0.y + c1 * v1.y + c2 * v2.y) * vv.y
              + (c0 * v0.z + c1 * v1.z + c2 * v2.z) * vv.z
              + (c0 * v0.w + c1 * v1.w + c2 * v2.w) * vv.w;

    if (lane < 32) {
        fx4 hv = ((const fx4*)(m_h + (size_t)row * HDIM))[lane];
        fx4 av = ((const fx4*)(a + OUTD))[lane];
        val += hv.x * av.x + hv.y * av.y + hv.z * av.z + hv.w * av.w;
    }

    #pragma unroll
    for (int off = 32; off > 0; off >>= 1) val += __shfl_down(val, off, 64);
    const float xi = __shfl(val, 0, 64);

    // ---- stream the row ----
    const fx4* y4 = (const fx4*)y;
    fx4* o = out + ((size_t)row << 11);        // 2048 fx4 per row
    #pragma unroll 4
    for (int c = lane; c < 2048; c += 128) {   // pairs: c and c+64
        fx4 ya = y4[c];
        fx4 yb = y4[c + 64];
        fx4 r0, r1;
        r0.x = mishf(xi + ya.x);
        r0.y = mishf(xi + ya.y);
        r0.z = mishf(xi + ya.z);
        r0.w = mishf(xi + ya.w);
        r1.x = mishf(xi + yb.x);
        r1.y = mishf(xi + yb.y);
        r1.z = mishf(xi + yb.z);
        r1.w = mishf(xi + yb.w);
        o[c]      = r0;
        o[c + 64] = r1;
    }
}

extern "C" void kernel_launch(void* const* d_in, const int* in_sizes, int n_in,
                              void* d_out, int out_size, void* d_ws, size_t ws_size,
                              hipStream_t stream) {
    const float* m   = (const float*)d_in[0];
    const float* m1  = (const float*)d_in[1];
    const float* m2  = (const float*)d_in[2];
    const float* m_h = (const float*)d_in[3];
    const float* d   = (const float*)d_in[4];
    const float* d1  = (const float*)d_in[5];
    const float* d2  = (const float*)d_in[6];
    const float* d_h = (const float*)d_in[7];
    const float* w_m = (const float*)d_in[8];
    const float* w_d = (const float*)d_in[9];
    const float* a_m = (const float*)d_in[10];
    const float* a_d = (const float*)d_in[11];
    const float* a   = (const float*)d_in[12];

    float* wsf = (float*)d_ws;
    float* v = wsf;           // 512 floats
    float* y = wsf + 512;     // 8192 floats

    compute_v_kernel<<<128, 256, 0, stream>>>(w_m, w_d, a, v);
    // 8192 d-rows, one wave each -> 2048 blocks
    compute_y_kernel<<<2048, 256, 0, stream>>>(d, d1, d2, d_h, a_d, a, v, y);
    // 4096 m-rows, one wave each -> 1024 blocks; x fused into the store stream
    mish_xbcast_kernel<<<1024, 256, 0, stream>>>(m, m1, m2, m_h, a_m, a, v, y,
                                                 (fx4*)d_out);
}